// Round 1
// baseline (2390.569 us; speedup 1.0000x reference)
//
#include <hip/hip_runtime.h>
#include <hip/hip_fp16.h>

#define TS 40
#define NB 2048
#define NU 1024
#define NI 1024
#define ND 2048
#define UD (1024 * 2048)

typedef _Float16 half8 __attribute__((ext_vector_type(8)));
typedef _Float16 half4v __attribute__((ext_vector_type(4)));
typedef float floatx4 __attribute__((ext_vector_type(4)));

__device__ __forceinline__ float tanh_fast(float v) {
  float e = __expf(2.0f * v);
  return 1.0f - 2.0f / (e + 1.0f);   // inf-safe: e=inf -> 1, e=0 -> -1
}

// Builds W_t^T in f16: Wout[tt][u][k] = sum_q Qw[k][u*8+q] * Bt[t0+tt][q]
// grid (D/32=64, U/32=32), 256 threads.
__global__ __launch_bounds__(256) void wprep(
    const float* __restrict__ Qw, const float* __restrict__ Bt,
    _Float16* __restrict__ W, int t0, int nt)
{
  __shared__ float ldsQ[32 * 257];
  __shared__ float ldsB[TS * 8];
  const int tid = threadIdx.x;
  const int k0 = blockIdx.x * 32;
  const int u0 = blockIdx.y * 32;
  for (int i = tid; i < TS * 8; i += 256) ldsB[i] = Bt[i];
  const float* qbase = Qw + (size_t)k0 * 8192 + (size_t)u0 * 8;
#pragma unroll
  for (int i = 0; i < 8; ++i) {
    int s = i * 256 + tid;
    int r = s >> 6, c4 = s & 63;
    float4 v = *(const float4*)(qbase + (size_t)r * 8192 + c4 * 4);
    float* d = &ldsQ[r * 257 + c4 * 4];
    d[0] = v.x; d[1] = v.y; d[2] = v.z; d[3] = v.w;
  }
  __syncthreads();
  const int kl = tid & 31;
  const int ug = tid >> 5;
#pragma unroll
  for (int p = 0; p < 4; ++p) {
    int uu = p * 8 + ug;
    float q[8];
#pragma unroll
    for (int j = 0; j < 8; ++j) q[j] = ldsQ[kl * 257 + uu * 8 + j];
    size_t obase = (size_t)(u0 + uu) * 2048 + k0 + kl;
    for (int tt = 0; tt < nt; ++tt) {
      const float* bt = &ldsB[(t0 + tt) * 8];
      float v = 0.f;
#pragma unroll
      for (int j = 0; j < 8; ++j) v += q[j] * bt[j];
      W[(size_t)tt * UD + obase] = (_Float16)v;
    }
  }
}

// One recurrent step: out[b][u] = tanh( sum_k cat[b][k]*W[k][u] + bias[u] )
// cat = [h_prev | x_t]; Wt passed transposed f16 [NU][ND].
// Tiles: BM=64 (b), BN=128 (u), BK=64. grid (32, 8), 256 threads (4 waves 2x2).
__global__ __launch_bounds__(256) void step_gemm(
    const float* __restrict__ xt,    // x + t*NI ; row stride TS*NI
    const float* __restrict__ hp,    // prev h base ; row stride hstride
    long hstride,
    const _Float16* __restrict__ Wt, // [NU][ND]
    const float* __restrict__ bias,
    float* __restrict__ outt)        // d_out + t*NU ; row stride TS*NU
{
  __shared__ _Float16 ldsA[2][64 * 64];
  __shared__ _Float16 ldsB[2][128 * 64];
  const int tid = threadIdx.x;
  const int b0 = blockIdx.x * 64;
  const int u0 = blockIdx.y * 128;
  const int lane = tid & 63;
  const int wv = tid >> 6;
  const int wm = wv >> 1, wn = wv & 1;
  const int l15 = lane & 15, lk = lane >> 4;

  float4 areg[4];
  uint4 breg[4];

  auto stage_load = [&](int kt) {
    const int k0 = kt * 64;
    const float* src; size_t stride; int koff;
    if (k0 < NU) { src = hp; stride = (size_t)hstride; koff = k0; }
    else { src = xt; stride = (size_t)TS * NI; koff = k0 - NU; }
#pragma unroll
    for (int i = 0; i < 4; ++i) {
      int s = i * 256 + tid;
      int r = s >> 4, c4 = s & 15;
      areg[i] = *(const float4*)(src + (size_t)(b0 + r) * stride + koff + c4 * 4);
    }
    const _Float16* wsrc = Wt + (size_t)u0 * 2048 + k0;
#pragma unroll
    for (int i = 0; i < 4; ++i) {
      int s = i * 256 + tid;
      int u = s >> 3, c8 = s & 7;
      breg[i] = *(const uint4*)(wsrc + (size_t)u * 2048 + c8 * 8);
    }
  };

  auto stage_write = [&](int buf) {
    char* pA = (char*)&ldsA[buf][0];
    char* pB = (char*)&ldsB[buf][0];
#pragma unroll
    for (int i = 0; i < 4; ++i) {
      int s = i * 256 + tid;
      int r = s >> 4, c4 = s & 15;
      half4v h;
      h[0] = (_Float16)areg[i].x; h[1] = (_Float16)areg[i].y;
      h[2] = (_Float16)areg[i].z; h[3] = (_Float16)areg[i].w;
      int off = (r * 128 + c4 * 8) ^ ((r & 7) << 4);
      *(half4v*)(pA + off) = h;
    }
#pragma unroll
    for (int i = 0; i < 4; ++i) {
      int s = i * 256 + tid;
      int u = s >> 3, c8 = s & 7;
      int off = (u * 128 + c8 * 16) ^ ((u & 7) << 4);
      *(uint4*)(pB + off) = breg[i];
    }
  };

  floatx4 acc[2][4] = {};

  auto compute = [&](int buf) {
    const char* pA = (const char*)&ldsA[buf][0];
    const char* pB = (const char*)&ldsB[buf][0];
#pragma unroll
    for (int kk = 0; kk < 2; ++kk) {
      half8 af[2], bf[4];
#pragma unroll
      for (int mf = 0; mf < 2; ++mf) {
        int r = wm * 32 + mf * 16 + l15;
        int off = r * 128 + ((((kk << 2) | lk) ^ (r & 7)) << 4);
        af[mf] = *(const half8*)(pA + off);
      }
#pragma unroll
      for (int nf = 0; nf < 4; ++nf) {
        int u = wn * 64 + nf * 16 + l15;
        int off = u * 128 + ((((kk << 2) | lk) ^ (u & 7)) << 4);
        bf[nf] = *(const half8*)(pB + off);
      }
#pragma unroll
      for (int mf = 0; mf < 2; ++mf)
#pragma unroll
        for (int nf = 0; nf < 4; ++nf)
          acc[mf][nf] =
              __builtin_amdgcn_mfma_f32_16x16x32_f16(af[mf], bf[nf], acc[mf][nf], 0, 0, 0);
    }
  };

  stage_load(0);
  stage_write(0);
  __syncthreads();
#pragma unroll 1
  for (int kt = 0; kt < 32; ++kt) {
    int cur = kt & 1;
    if (kt + 1 < 32) stage_load(kt + 1);   // issue next tile's global loads early
    compute(cur);                           // MFMAs hide load latency
    if (kt + 1 < 32) stage_write(cur ^ 1);  // vmcnt waits via reg deps
    __syncthreads();
  }

  // epilogue: C/D frag layout col=lane&15, row=(lane>>4)*4+j (m89-verified)
#pragma unroll
  for (int mf = 0; mf < 2; ++mf) {
#pragma unroll
    for (int nf = 0; nf < 4; ++nf) {
      int u = u0 + wn * 64 + nf * 16 + l15;
      float bv = bias[u];
      int brow = b0 + wm * 32 + mf * 16 + (lk << 2);
#pragma unroll
      for (int j = 0; j < 4; ++j) {
        float pre = acc[mf][nf][j] + bv;
        outt[(size_t)(brow + j) * (TS * NU) + u] = tanh_fast(pre);
      }
    }
  }
}

extern "C" void kernel_launch(void* const* d_in, const int* in_sizes, int n_in,
                              void* d_out, int out_size, void* d_ws, size_t ws_size,
                              hipStream_t stream) {
  const float* x    = (const float*)d_in[0];
  const float* h0   = (const float*)d_in[1];
  const float* Qw   = (const float*)d_in[2];
  const float* bias = (const float*)d_in[3];
  const float* Bt   = (const float*)d_in[4];
  float* out = (float*)d_out;

  _Float16* W = (_Float16*)d_ws;
  const size_t wall_bytes = (size_t)UD * TS * sizeof(_Float16);  // 167.8 MB
  const bool big = ws_size >= wall_bytes;

  if (big) {
    wprep<<<dim3(64, 32), 256, 0, stream>>>(Qw, Bt, W, 0, TS);
  }
  for (int t = 0; t < TS; ++t) {
    const _Float16* Wtp;
    if (big) {
      Wtp = W + (size_t)t * UD;
    } else {
      wprep<<<dim3(64, 32), 256, 0, stream>>>(Qw, Bt, W, t, 1);
      Wtp = W;
    }
    const float* hp = (t == 0) ? h0 : out + (size_t)(t - 1) * NU;
    long hstride = (t == 0) ? NU : (long)TS * NU;
    step_gemm<<<dim3(32, 8), 256, 0, stream>>>(
        x + (size_t)t * NI, hp, hstride, Wtp, bias, out + (size_t)t * NU);
  }
}